// Round 4
// baseline (157.352 us; speedup 1.0000x reference)
//
#include <hip/hip_runtime.h>

// DyGFormer co-occurrence encoder, collapsed:
//   counts are per-batch histograms; the 2-layer MLP of a scalar count is a
//   513-entry lookup table T'[c] = relu(c*W1+b1)@W2 + b2 (b2 folded in).
//   out_src[b,l,:] = T'[hist_src[sid]] + T'[hist_dst[sid]]   (sid==0 -> c=0)
//   out_dst[b,l,:] = T'[hist_src[did]] + T'[hist_dst[did]]
// Memory-bound on the 134 MB fp32 output write (floor ~21 us at 6.3 TB/s).
//
// Structure: prep (LUT + per-batch packed counts, once) -> encode (pure
// stream: no LDS, no barriers; gather 4 L1-hot T rows, NT-store 2 rows).

#define BB      256
#define LL      512
#define DD      128
#define NNODES  1024
#define CMAX    512            // max possible count
#define TBLOCKS 257            // table blocks (2 c-values each, 513 total)

typedef float f4x __attribute__((ext_vector_type(4)));  // native vec: NT-store OK

// blocks [0, TBLOCKS):    T'[c][e] = b2[e] + sum_d relu(c*W1[d]+b1[d])*W2[d*D+e]
// blocks [TBLOCKS, +BB):  per-batch histograms -> packed counts uint2 per (b,l)
__global__ __launch_bounds__(256) void prep_kernel(
    const int* __restrict__ src_ids, const int* __restrict__ dst_ids,
    const float* __restrict__ W1, const float* __restrict__ b1,
    const float* __restrict__ W2, const float* __restrict__ b2,
    float* __restrict__ T, uint2* __restrict__ cnt4) {
  __shared__ int hist[2 * NNODES];       // also reused as h[2][DD] for table
  const int tid = threadIdx.x;

  if (blockIdx.x < TBLOCKS) {
    // ---- LUT build: two c-values per block ----
    float* h = (float*)hist;             // h[half*DD + e]
    const int half = tid >> 7;           // 0,1
    const int e    = tid & (DD - 1);
    const int c    = blockIdx.x * 2 + half;
    const int cc   = (c <= CMAX) ? c : CMAX;   // clamp (block 256 half 1)
    h[half * DD + e] = fmaxf((float)cc * W1[e] + b1[e], 0.0f);
    __syncthreads();
    float acc = b2[e];
#pragma unroll 16
    for (int d = 0; d < DD; ++d) acc = fmaf(h[half * DD + d], W2[d * DD + e], acc);
    if (c <= CMAX) T[c * DD + e] = acc;
  } else {
    // ---- per-batch histogram + packed counts ----
    const int batch = blockIdx.x - TBLOCKS;
#pragma unroll
    for (int i = tid; i < 2 * NNODES; i += 256) hist[i] = 0;
    __syncthreads();
    const int* sb = src_ids + batch * LL;
    const int* db = dst_ids + batch * LL;
#pragma unroll
    for (int i = tid; i < LL; i += 256) {
      atomicAdd(&hist[sb[i]], 1);
      atomicAdd(&hist[NNODES + db[i]], 1);
    }
    __syncthreads();
#pragma unroll
    for (int l = tid; l < LL; l += 256) {
      const int sid = sb[l];
      const int did = db[l];
      const unsigned css = sid ? (unsigned)hist[sid] : 0u;
      const unsigned csd = sid ? (unsigned)hist[NNODES + sid] : 0u;
      const unsigned cds = did ? (unsigned)hist[did] : 0u;
      const unsigned cdd = did ? (unsigned)hist[NNODES + did] : 0u;
      cnt4[batch * LL + l] = make_uint2(css | (csd << 16), cds | (cdd << 16));
    }
  }
}

// Pure streaming encode: 8 rows per 256-thread iteration; 32-lane group per row.
__global__ __launch_bounds__(256) void encode_kernel(
    const uint2* __restrict__ cnt4, const float* __restrict__ T,
    float* __restrict__ out) {
  const int lane = threadIdx.x & 31;   // f4x index within a 128-float row
  const int rsub = threadIdx.x >> 5;   // 0..7
  const size_t OUT_OFF = (size_t)BB * LL * DD;
  const int NGROUPS = (BB * LL) / 8;   // 16384 groups of 8 rows

  for (int g = blockIdx.x; g < NGROUPS; g += gridDim.x) {
    const int p = g * 8 + rsub;        // row index in [0, B*L)
    const uint2 c4 = cnt4[p];
    const int c_ss = c4.x & 0xffff, c_sd = c4.x >> 16;
    const int c_ds = c4.y & 0xffff, c_dd = c4.y >> 16;
    const f4x a = ((const f4x*)(T + c_ss * DD))[lane];
    const f4x b = ((const f4x*)(T + c_sd * DD))[lane];
    const f4x c = ((const f4x*)(T + c_ds * DD))[lane];
    const f4x d = ((const f4x*)(T + c_dd * DD))[lane];
    const f4x vs = a + b;
    const f4x vd = c + d;
    __builtin_nontemporal_store(vs, ((f4x*)(out + (size_t)p * DD)) + lane);
    __builtin_nontemporal_store(vd, ((f4x*)(out + OUT_OFF + (size_t)p * DD)) + lane);
  }
}

extern "C" void kernel_launch(void* const* d_in, const int* in_sizes, int n_in,
                              void* d_out, int out_size, void* d_ws, size_t ws_size,
                              hipStream_t stream) {
  const int*   src = (const int*)d_in[0];
  const int*   dst = (const int*)d_in[1];
  const float* W1  = (const float*)d_in[2];  // (1, D)
  const float* b1  = (const float*)d_in[3];  // (D,)
  const float* W2  = (const float*)d_in[4];  // (D, D) row-major
  const float* b2  = (const float*)d_in[5];  // (D,)
  float* out  = (float*)d_out;
  float* T    = (float*)d_ws;                  // 513*128 fp32 = 262,656 B
  uint2* cnt4 = (uint2*)(T + 66048);           // offset 264,192 B (8B-aligned); 1 MB

  prep_kernel<<<TBLOCKS + BB, 256, 0, stream>>>(src, dst, W1, b1, W2, b2, T, cnt4);
  encode_kernel<<<2048, 256, 0, stream>>>(cnt4, T, out);
}